// Round 14
// baseline (81.679 us; speedup 1.0000x reference)
//
#include <hip/hip_runtime.h>

typedef __attribute__((ext_vector_type(8))) short bf16x8;
typedef __attribute__((ext_vector_type(4))) float f32x4;

static constexpr int N_NODES = 8192;   // B*L
static constexpr int FEAT    = 128;
static constexpr int NB      = 16;     // nodes per fused block
static constexpr int NBLK    = N_NODES / NB;   // 512 blocks
static constexpr int XS      = 136;    // LDS X row stride (bf16): 272B, 16B-aligned
static constexpr int F8_BLOCKS = 3125; // 100000*128 fp8 bytes / (256 thr * 16 B)

__device__ __forceinline__ unsigned short f2bf(float f) {
    unsigned u = __builtin_bit_cast(unsigned, f);
    u += 0x7FFFu + ((u >> 16) & 1u);   // round-to-nearest-even
    return (unsigned short)(u >> 16);
}
// f32 -> e4m3fn, RNE, satfinite (r13-verified). af*2^-120 puts the e4m3
// em-field at f32 bits [26:20] (exact incl. subnormals); round at bit 20.
__device__ __forceinline__ unsigned f2fp8(float f) {
    unsigned u = __builtin_bit_cast(unsigned, f);
    unsigned s = (u >> 24) & 0x80u;
    float af = __builtin_bit_cast(float, u & 0x7fffffffu);
    if (!(af < 448.f)) af = 448.f;
    unsigned q = __builtin_bit_cast(unsigned, af * 0x1p-120f);
    unsigned b = (q + 0x7FFFFu + ((q >> 20) & 1u)) >> 20;
    return s | b;
}
// e4m3fn decode+accumulate (r13-verified): byte to top, ashr 4, mask, fma 2^120.
__device__ __forceinline__ void acc8f8(float* a, const uint2 v) {
#pragma unroll
    for (int i = 0; i < 4; ++i) {
        unsigned t = v.x << (24 - 8 * i);
        unsigned w = (unsigned)((int)t >> 4) & 0x87F00000u;
        a[i] = fmaf(__builtin_bit_cast(float, w), 0x1p120f, a[i]);
    }
#pragma unroll
    for (int i = 0; i < 4; ++i) {
        unsigned t = v.y << (24 - 8 * i);
        unsigned w = (unsigned)((int)t >> 4) & 0x87F00000u;
        a[4 + i] = fmaf(__builtin_bit_cast(float, w), 0x1p120f, a[4 + i]);
    }
}
__device__ __forceinline__ uint4 pack8(const float* a, float sc) {
    uint4 o;
    o.x = (unsigned)f2bf(a[0] * sc) | ((unsigned)f2bf(a[1] * sc) << 16);
    o.y = (unsigned)f2bf(a[2] * sc) | ((unsigned)f2bf(a[3] * sc) << 16);
    o.z = (unsigned)f2bf(a[4] * sc) | ((unsigned)f2bf(a[5] * sc) << 16);
    o.w = (unsigned)f2bf(a[6] * sc) | ((unsigned)f2bf(a[7] * sc) << 16);
    return o;
}

// ---------------- Kernel 0: pack features fp32 -> fp8, W fp32 -> bf16 ----------------
__global__ void __launch_bounds__(256) pack_all(
    const float* __restrict__ feat, const float* __restrict__ lw,
    unsigned char* __restrict__ T8, unsigned short* __restrict__ Wp)
{
    const int b = blockIdx.x;
    if (b < F8_BLOCKS) {
        const size_t i = (size_t)b * 256 + threadIdx.x;   // handles 16 floats
        const f32x4* src = (const f32x4*)feat + i * 4;
        uint4 p;
        unsigned* pw = (unsigned*)&p;
#pragma unroll
        for (int h = 0; h < 4; ++h) {
            const f32x4 v = __builtin_nontemporal_load(src + h);
            pw[h] = f2fp8(v[0]) | (f2fp8(v[1]) << 8) | (f2fp8(v[2]) << 16) | (f2fp8(v[3]) << 24);
        }
        ((uint4*)T8)[i] = p;
    } else {
        const int i = (b - F8_BLOCKS) * 256 + threadIdx.x;
        const float4 v = ((const float4*)lw)[i];
        ushort4 o;
        o.x = f2bf(v.x); o.y = f2bf(v.y); o.z = f2bf(v.z); o.w = f2bf(v.w);
        ((ushort4*)Wp)[i] = o;
    }
}

// ---------------- Fused: gather (fp8, pipelined) -> LDS X -> MFMA GEMM + ReLU ----
__global__ void __launch_bounds__(256) fused_enc(
    const unsigned char*  __restrict__ T8,
    const float* __restrict__ featF,
    const int*   __restrict__ nodes,
    const int*   __restrict__ n1,
    const int*   __restrict__ n2,
    const unsigned short* __restrict__ Wp,
    float* __restrict__ out)
{
    __shared__ int nfs[NB];
    __shared__ int sm_m[NB][10];
    __shared__ int idx[NB][112];              // [0..9]=1hop, [10..109]=2hop, [110]=self
    __shared__ unsigned short X[3 * NB][XS];  // 48 x 136 bf16

    const int blk = blockIdx.x;
    const int tid = threadIdx.x;

    // ---- phase 1: indices (r11-verified) ----
    if (tid < NB) nfs[tid] = nodes[blk * NB + tid];
    __syncthreads();
    if (tid < NB * 10) {                       // 160 threads: 1-hop
        const int i = tid / 10, s = tid - (tid / 10) * 10;
        idx[i][s] = n1[nfs[i] * 10 + s];
    }
    if (tid >= 96) {                           // 160 threads: 2-hop seeds
        const int t = tid - 96;
        const int i = t / 10, s = t - (t / 10) * 10;
        sm_m[i][s] = n2[nfs[i] * 10 + s];
    }
    if (tid < NB) idx[tid][110] = nfs[tid];
    __syncthreads();
    for (int t = tid; t < NB * 100; t += 256) { // 1600 two-hop rows
        const int i = t / 100, rr = t - (t / 100) * 100;
        idx[i][10 + rr] = n1[sm_m[i][rr / 10] * 10 + (rr - (rr / 10) * 10)];
    }
    __syncthreads();

    // ---- phase 2: gather, ping-pong pipelined fp8 chunks ----
    {
        const int g = tid >> 4;    // node_local 0..15
        const int l = tid & 15;    // dims l*8 .. l*8+7
        const unsigned char* Tl8 = T8 + l * 8;

        float aA[8] = {0,0,0,0,0,0,0,0};
        float aB[8] = {0,0,0,0,0,0,0,0};
        uint2 va[10], vb[10];

        // prologue: issue chunk 0 (1-hop) + self (fp32, exact) loads
#pragma unroll
        for (int s = 0; s < 10; ++s)
            va[s] = *(const uint2*)(Tl8 + (size_t)idx[g][s] * FEAT);
        const float* Fs = featF + (size_t)idx[g][110] * FEAT + l * 8;
        const f32x4 s0 = *(const f32x4*)Fs;
        const f32x4 s1 = *(const f32x4*)(Fs + 4);

        // pipeline: load chunk(2cc+1) -> acc va -> load chunk(2cc+2) -> acc vb
#pragma unroll
        for (int cc = 0; cc < 5; ++cc) {
            const int cA = 2 * cc + 1, cB = 2 * cc + 2;
#pragma unroll
            for (int s = 0; s < 10; ++s)
                vb[s] = *(const uint2*)(Tl8 + (size_t)idx[g][cA * 10 + s] * FEAT);
#pragma unroll
            for (int s = 0; s < 10; ++s) {
                if (cc == 0) acc8f8(aA, va[s]); else acc8f8(aB, va[s]);
            }
#pragma unroll
            for (int s = 0; s < 10; ++s)
                va[s] = *(const uint2*)(Tl8 + (size_t)idx[g][cB * 10 + s] * FEAT);
#pragma unroll
            for (int s = 0; s < 10; ++s) acc8f8(aB, vb[s]);
        }
#pragma unroll
        for (int s = 0; s < 10; ++s) acc8f8(aB, va[s]);   // chunk 10 drain

        float aS[8] = {s0[0], s0[1], s0[2], s0[3], s1[0], s1[1], s1[2], s1[3]};
        *(uint4*)&X[g * 3 + 2][l * 8] = pack8(aS, 1.0f);
        *(uint4*)&X[g * 3 + 0][l * 8] = pack8(aA, 0.1f);
        *(uint4*)&X[g * 3 + 1][l * 8] = pack8(aB, 0.01f);
    }
    __syncthreads();

    // ---- phase 3: GEMM M=48 x N=1024 x K=128 + ReLU (r11-verified verbatim) ----
    const int wave = tid >> 6;
    const int lane = tid & 63;
    const int r = lane & 15;   // A row / B col within 16-tile
    const int q = lane >> 4;   // k-slot (8 contiguous K elems)

#pragma unroll
    for (int ch = 0; ch < 4; ++ch) {
        const int yBase = wave * 256 + ch * 64;
        f32x4 acc[3][4];
#pragma unroll
        for (int mt = 0; mt < 3; ++mt)
#pragma unroll
            for (int nj = 0; nj < 4; ++nj) acc[mt][nj] = (f32x4){0.f, 0.f, 0.f, 0.f};

#pragma unroll
        for (int k0 = 0; k0 < 4; ++k0) {
            bf16x8 a[3], b[4];
#pragma unroll
            for (int mt = 0; mt < 3; ++mt)
                a[mt] = *(const bf16x8*)&X[mt * 16 + r][k0 * 32 + q * 8];
#pragma unroll
            for (int nj = 0; nj < 4; ++nj)
                b[nj] = *(const bf16x8*)(Wp + (size_t)(yBase + nj * 16 + r) * FEAT
                                            + q * 8 + k0 * 32);
#pragma unroll
            for (int mt = 0; mt < 3; ++mt)
#pragma unroll
                for (int nj = 0; nj < 4; ++nj)
                    acc[mt][nj] = __builtin_amdgcn_mfma_f32_16x16x32_bf16(
                        a[mt], b[nj], acc[mt][nj], 0, 0, 0);
        }

        // scattered epilogue (r11-verified): C/D row = q*4+i, col = r.
#pragma unroll
        for (int mt = 0; mt < 3; ++mt) {
#pragma unroll
            for (int i = 0; i < 4; ++i) {
                const int xl = mt * 16 + q * 4 + i;   // 0..47
                const int nl = xl / 3;
                const int j  = xl - nl * 3;
                float* orow = out + (size_t)(blk * NB + nl) * 3072 + j * 128;
#pragma unroll
                for (int nj = 0; nj < 4; ++nj) {
                    const int y = yBase + nj * 16 + r;
                    const int c = y >> 7;
                    const int k = y & 127;
                    orow[c * 384 + k] = fmaxf(acc[mt][nj][i], 0.f);
                }
            }
        }
    }
}

extern "C" void kernel_launch(void* const* d_in, const int* in_sizes, int n_in,
                              void* d_out, int out_size, void* d_ws, size_t ws_size,
                              hipStream_t stream) {
    const float* features = (const float*)d_in[0];   // [100000,128] f32
    const float* lw       = (const float*)d_in[1];   // [8,128,128]  f32
    const int*   nodes    = (const int*)d_in[2];     // [1024,8]     i32
    const int*   n1       = (const int*)d_in[3];     // [100000,10]  i32
    const int*   n2       = (const int*)d_in[4];     // [100000,10]  i32
    float*       out      = (float*)d_out;           // [1024,8,8,384] f32

    unsigned short* Wp = (unsigned short*)d_ws;              // 1024*128 bf16 = 256 KB
    unsigned char*  T8 = (unsigned char*)(Wp + (size_t)1024 * FEAT);  // 12.8 MB fp8

    pack_all<<<F8_BLOCKS + 128, 256, 0, stream>>>(features, lw, T8, Wp);
    fused_enc<<<NBLK, 256, 0, stream>>>(T8, features, nodes, n1, n2, Wp, out);
}

// Round 15
// 74.768 us; speedup vs baseline: 1.0924x; 1.0924x over previous
//
#include <hip/hip_runtime.h>

typedef __attribute__((ext_vector_type(8))) short bf16x8;
typedef __attribute__((ext_vector_type(4))) float f32x4;

static constexpr int N_NODES = 8192;   // B*L
static constexpr int FEAT    = 128;
static constexpr int NB      = 16;     // nodes per fused block
static constexpr int NBLK    = N_NODES / NB;   // 512 blocks
static constexpr int XS      = 136;    // LDS X row stride (bf16): 272B, 16B-aligned
static constexpr int F8_BLOCKS = 3125; // 100000*128 fp8 bytes / (256 thr * 16 B)

__device__ __forceinline__ unsigned short f2bf(float f) {
    unsigned u = __builtin_bit_cast(unsigned, f);
    u += 0x7FFFu + ((u >> 16) & 1u);   // round-to-nearest-even
    return (unsigned short)(u >> 16);
}
// f32 -> e4m3fn, RNE, satfinite (r13-verified). af*2^-120 puts the e4m3
// em-field at f32 bits [26:20] (exact incl. subnormals); round at bit 20.
__device__ __forceinline__ unsigned f2fp8(float f) {
    unsigned u = __builtin_bit_cast(unsigned, f);
    unsigned s = (u >> 24) & 0x80u;
    float af = __builtin_bit_cast(float, u & 0x7fffffffu);
    if (!(af < 448.f)) af = 448.f;
    unsigned q = __builtin_bit_cast(unsigned, af * 0x1p-120f);
    unsigned b = (q + 0x7FFFFu + ((q >> 20) & 1u)) >> 20;
    return s | b;
}
// e4m3fn decode+accumulate (r13-verified): byte to top, ashr 4, mask, fma 2^120.
__device__ __forceinline__ void acc8f8(float* a, const uint2 v) {
#pragma unroll
    for (int i = 0; i < 4; ++i) {
        unsigned t = v.x << (24 - 8 * i);
        unsigned w = (unsigned)((int)t >> 4) & 0x87F00000u;
        a[i] = fmaf(__builtin_bit_cast(float, w), 0x1p120f, a[i]);
    }
#pragma unroll
    for (int i = 0; i < 4; ++i) {
        unsigned t = v.y << (24 - 8 * i);
        unsigned w = (unsigned)((int)t >> 4) & 0x87F00000u;
        a[4 + i] = fmaf(__builtin_bit_cast(float, w), 0x1p120f, a[4 + i]);
    }
}
__device__ __forceinline__ uint4 pack8(const float* a, float sc) {
    uint4 o;
    o.x = (unsigned)f2bf(a[0] * sc) | ((unsigned)f2bf(a[1] * sc) << 16);
    o.y = (unsigned)f2bf(a[2] * sc) | ((unsigned)f2bf(a[3] * sc) << 16);
    o.z = (unsigned)f2bf(a[4] * sc) | ((unsigned)f2bf(a[5] * sc) << 16);
    o.w = (unsigned)f2bf(a[6] * sc) | ((unsigned)f2bf(a[7] * sc) << 16);
    return o;
}

// ---------------- Kernel 0: pack features fp32 -> fp8, W fp32 -> bf16 ----------------
__global__ void __launch_bounds__(256) pack_all(
    const float* __restrict__ feat, const float* __restrict__ lw,
    unsigned char* __restrict__ T8, unsigned short* __restrict__ Wp)
{
    const int b = blockIdx.x;
    if (b < F8_BLOCKS) {
        const size_t i = (size_t)b * 256 + threadIdx.x;   // handles 16 floats
        const f32x4* src = (const f32x4*)feat + i * 4;
        uint4 p;
        unsigned* pw = (unsigned*)&p;
#pragma unroll
        for (int h = 0; h < 4; ++h) {
            const f32x4 v = __builtin_nontemporal_load(src + h);
            pw[h] = f2fp8(v[0]) | (f2fp8(v[1]) << 8) | (f2fp8(v[2]) << 16) | (f2fp8(v[3]) << 24);
        }
        ((uint4*)T8)[i] = p;
    } else {
        const int i = (b - F8_BLOCKS) * 256 + threadIdx.x;
        const float4 v = ((const float4*)lw)[i];
        ushort4 o;
        o.x = f2bf(v.x); o.y = f2bf(v.y); o.z = f2bf(v.z); o.w = f2bf(v.w);
        ((ushort4*)Wp)[i] = o;
    }
}

// ---------------- Fused: gather (fp8, r13-loop) -> LDS X -> MFMA GEMM + ReLU ----
__global__ void __launch_bounds__(256) fused_enc(
    const unsigned char*  __restrict__ T8,
    const float* __restrict__ featF,
    const int*   __restrict__ nodes,
    const int*   __restrict__ n1,
    const int*   __restrict__ n2,
    const unsigned short* __restrict__ Wp,
    float* __restrict__ out)
{
    __shared__ int nfs[NB];
    __shared__ int sm_m[NB][10];
    __shared__ int idx[NB][112];              // [0..9]=1hop, [10..109]=2hop, [110]=self
    __shared__ unsigned short X[3 * NB][XS];  // 48 x 136 bf16

    const int blk = blockIdx.x;
    const int tid = threadIdx.x;

    // ---- phase 1: indices (r11-verified) ----
    if (tid < NB) nfs[tid] = nodes[blk * NB + tid];
    __syncthreads();
    if (tid < NB * 10) {                       // 160 threads: 1-hop
        const int i = tid / 10, s = tid - (tid / 10) * 10;
        idx[i][s] = n1[nfs[i] * 10 + s];
    }
    if (tid >= 96) {                           // 160 threads: 2-hop seeds
        const int t = tid - 96;
        const int i = t / 10, s = t - (t / 10) * 10;
        sm_m[i][s] = n2[nfs[i] * 10 + s];
    }
    if (tid < NB) idx[tid][110] = nfs[tid];
    __syncthreads();
    for (int t = tid; t < NB * 100; t += 256) { // 1600 two-hop rows
        const int i = t / 100, rr = t - (t / 100) * 100;
        idx[i][10 + rr] = n1[sm_m[i][rr / 10] * 10 + (rr - (rr / 10) * 10)];
    }
    __syncthreads();

    // ---- phase 2: gather (r13 sequential-chunk loop, all-fp8 + fp32 self) ----
    {
        const int g = tid >> 4;    // node_local 0..15
        const int l = tid & 15;    // dims l*8 .. l*8+7
        const unsigned char* Tl8 = T8 + l * 8;

        float aA[8] = {0,0,0,0,0,0,0,0};
        float aB[8] = {0,0,0,0,0,0,0,0};

        // self row (fp32, exact) — issue early, consumed at the end
        const float* Fs = featF + (size_t)idx[g][110] * FEAT + l * 8;
        const f32x4 s0 = *(const f32x4*)Fs;
        const f32x4 s1 = *(const f32x4*)(Fs + 4);

        {   // chunk 0: rows 0..9 -> 1-hop (fp8)
            uint2 v[10];
#pragma unroll
            for (int s = 0; s < 10; ++s)
                v[s] = *(const uint2*)(Tl8 + (size_t)idx[g][s] * FEAT);
#pragma unroll
            for (int s = 0; s < 10; ++s) acc8f8(aA, v[s]);
        }
        // chunks 1..10: rows 10..109 -> 2-hop (fp8)
#pragma unroll
        for (int c = 1; c <= 10; ++c) {
            uint2 v[10];
#pragma unroll
            for (int s = 0; s < 10; ++s)
                v[s] = *(const uint2*)(Tl8 + (size_t)idx[g][c * 10 + s] * FEAT);
#pragma unroll
            for (int s = 0; s < 10; ++s) acc8f8(aB, v[s]);
        }

        float aS[8] = {s0[0], s0[1], s0[2], s0[3], s1[0], s1[1], s1[2], s1[3]};
        *(uint4*)&X[g * 3 + 2][l * 8] = pack8(aS, 1.0f);
        *(uint4*)&X[g * 3 + 0][l * 8] = pack8(aA, 0.1f);
        *(uint4*)&X[g * 3 + 1][l * 8] = pack8(aB, 0.01f);
    }
    __syncthreads();

    // ---- phase 3: GEMM M=48 x N=1024 x K=128 + ReLU (r11-verified verbatim) ----
    const int wave = tid >> 6;
    const int lane = tid & 63;
    const int r = lane & 15;   // A row / B col within 16-tile
    const int q = lane >> 4;   // k-slot (8 contiguous K elems)

#pragma unroll
    for (int ch = 0; ch < 4; ++ch) {
        const int yBase = wave * 256 + ch * 64;
        f32x4 acc[3][4];
#pragma unroll
        for (int mt = 0; mt < 3; ++mt)
#pragma unroll
            for (int nj = 0; nj < 4; ++nj) acc[mt][nj] = (f32x4){0.f, 0.f, 0.f, 0.f};

#pragma unroll
        for (int k0 = 0; k0 < 4; ++k0) {
            bf16x8 a[3], b[4];
#pragma unroll
            for (int mt = 0; mt < 3; ++mt)
                a[mt] = *(const bf16x8*)&X[mt * 16 + r][k0 * 32 + q * 8];
#pragma unroll
            for (int nj = 0; nj < 4; ++nj)
                b[nj] = *(const bf16x8*)(Wp + (size_t)(yBase + nj * 16 + r) * FEAT
                                            + q * 8 + k0 * 32);
#pragma unroll
            for (int mt = 0; mt < 3; ++mt)
#pragma unroll
                for (int nj = 0; nj < 4; ++nj)
                    acc[mt][nj] = __builtin_amdgcn_mfma_f32_16x16x32_bf16(
                        a[mt], b[nj], acc[mt][nj], 0, 0, 0);
        }

        // scattered epilogue (r11-verified): C/D row = q*4+i, col = r.
#pragma unroll
        for (int mt = 0; mt < 3; ++mt) {
#pragma unroll
            for (int i = 0; i < 4; ++i) {
                const int xl = mt * 16 + q * 4 + i;   // 0..47
                const int nl = xl / 3;
                const int j  = xl - nl * 3;
                float* orow = out + (size_t)(blk * NB + nl) * 3072 + j * 128;
#pragma unroll
                for (int nj = 0; nj < 4; ++nj) {
                    const int y = yBase + nj * 16 + r;
                    const int c = y >> 7;
                    const int k = y & 127;
                    orow[c * 384 + k] = fmaxf(acc[mt][nj][i], 0.f);
                }
            }
        }
    }
}

extern "C" void kernel_launch(void* const* d_in, const int* in_sizes, int n_in,
                              void* d_out, int out_size, void* d_ws, size_t ws_size,
                              hipStream_t stream) {
    const float* features = (const float*)d_in[0];   // [100000,128] f32
    const float* lw       = (const float*)d_in[1];   // [8,128,128]  f32
    const int*   nodes    = (const int*)d_in[2];     // [1024,8]     i32
    const int*   n1       = (const int*)d_in[3];     // [100000,10]  i32
    const int*   n2       = (const int*)d_in[4];     // [100000,10]  i32
    float*       out      = (float*)d_out;           // [1024,8,8,384] f32

    unsigned short* Wp = (unsigned short*)d_ws;              // 1024*128 bf16 = 256 KB
    unsigned char*  T8 = (unsigned char*)(Wp + (size_t)1024 * FEAT);  // 12.8 MB fp8

    pack_all<<<F8_BLOCKS + 128, 256, 0, stream>>>(features, lw, T8, Wp);
    fused_enc<<<NBLK, 256, 0, stream>>>(T8, features, nodes, n1, n2, Wp, out);
}

// Round 16
// 73.364 us; speedup vs baseline: 1.1133x; 1.0191x over previous
//
#include <hip/hip_runtime.h>

typedef __attribute__((ext_vector_type(8))) short bf16x8;
typedef __attribute__((ext_vector_type(4))) float f32x4;

static constexpr int N_NODES = 8192;   // B*L
static constexpr int FEAT    = 128;
static constexpr int NB      = 16;     // nodes per fused block
static constexpr int NBLK    = N_NODES / NB;   // 512 blocks
static constexpr int XS      = 136;    // LDS X row stride (bf16): 272B, 16B-aligned
static constexpr int F8_BLOCKS = 3125; // 100000*128 fp8 bytes / (256 thr * 16 B)

__device__ __forceinline__ unsigned short f2bf(float f) {
    unsigned u = __builtin_bit_cast(unsigned, f);
    u += 0x7FFFu + ((u >> 16) & 1u);   // round-to-nearest-even
    return (unsigned short)(u >> 16);
}
// f32 -> e4m3fn, RNE, satfinite (r13-verified). af*2^-120 puts the e4m3
// em-field at f32 bits [26:20] (exact incl. subnormals); round at bit 20.
__device__ __forceinline__ unsigned f2fp8(float f) {
    unsigned u = __builtin_bit_cast(unsigned, f);
    unsigned s = (u >> 24) & 0x80u;
    float af = __builtin_bit_cast(float, u & 0x7fffffffu);
    if (!(af < 448.f)) af = 448.f;
    unsigned q = __builtin_bit_cast(unsigned, af * 0x1p-120f);
    unsigned b = (q + 0x7FFFFu + ((q >> 20) & 1u)) >> 20;
    return s | b;
}
// e4m3fn decode+accumulate (r13-verified): byte to top, ashr 4, mask, fma 2^120.
__device__ __forceinline__ void acc8f8(float* a, const uint2 v) {
#pragma unroll
    for (int i = 0; i < 4; ++i) {
        unsigned t = v.x << (24 - 8 * i);
        unsigned w = (unsigned)((int)t >> 4) & 0x87F00000u;
        a[i] = fmaf(__builtin_bit_cast(float, w), 0x1p120f, a[i]);
    }
#pragma unroll
    for (int i = 0; i < 4; ++i) {
        unsigned t = v.y << (24 - 8 * i);
        unsigned w = (unsigned)((int)t >> 4) & 0x87F00000u;
        a[4 + i] = fmaf(__builtin_bit_cast(float, w), 0x1p120f, a[4 + i]);
    }
}
__device__ __forceinline__ uint4 pack8(const float* a, float sc) {
    uint4 o;
    o.x = (unsigned)f2bf(a[0] * sc) | ((unsigned)f2bf(a[1] * sc) << 16);
    o.y = (unsigned)f2bf(a[2] * sc) | ((unsigned)f2bf(a[3] * sc) << 16);
    o.z = (unsigned)f2bf(a[4] * sc) | ((unsigned)f2bf(a[5] * sc) << 16);
    o.w = (unsigned)f2bf(a[6] * sc) | ((unsigned)f2bf(a[7] * sc) << 16);
    return o;
}

// ---------------- Kernel 0: pack features fp32 -> fp8, W fp32 -> bf16 ----------------
__global__ void __launch_bounds__(256) pack_all(
    const float* __restrict__ feat, const float* __restrict__ lw,
    unsigned char* __restrict__ T8, unsigned short* __restrict__ Wp)
{
    const int b = blockIdx.x;
    if (b < F8_BLOCKS) {
        const size_t i = (size_t)b * 256 + threadIdx.x;   // handles 16 floats
        const f32x4* src = (const f32x4*)feat + i * 4;
        uint4 p;
        unsigned* pw = (unsigned*)&p;
#pragma unroll
        for (int h = 0; h < 4; ++h) {
            const f32x4 v = __builtin_nontemporal_load(src + h);
            pw[h] = f2fp8(v[0]) | (f2fp8(v[1]) << 8) | (f2fp8(v[2]) << 16) | (f2fp8(v[3]) << 24);
        }
        ((uint4*)T8)[i] = p;
    } else {
        const int i = (b - F8_BLOCKS) * 256 + threadIdx.x;
        const float4 v = ((const float4*)lw)[i];
        ushort4 o;
        o.x = f2bf(v.x); o.y = f2bf(v.y); o.z = f2bf(v.z); o.w = f2bf(v.w);
        ((ushort4*)Wp)[i] = o;
    }
}

// ---------------- Fused: gather (fp8, r13-loop) -> LDS X -> MFMA GEMM + ReLU ----
// __launch_bounds__(256,4): pin VGPR <= 128 (r15 lesson: 132 VGPR halved occupancy)
__global__ void __launch_bounds__(256, 4) fused_enc(
    const unsigned char*  __restrict__ T8,
    const float* __restrict__ featF,
    const int*   __restrict__ nodes,
    const int*   __restrict__ n1,
    const int*   __restrict__ n2,
    const unsigned short* __restrict__ Wp,
    float* __restrict__ out)
{
    __shared__ int nfs[NB];
    __shared__ int sm_m[NB][10];
    __shared__ int idx[NB][112];              // [0..9]=1hop, [10..109]=2hop, [110]=self
    __shared__ unsigned short X[3 * NB][XS];  // 48 x 136 bf16

    const int blk = blockIdx.x;
    const int tid = threadIdx.x;

    // ---- phase 1: indices (r11-verified) ----
    if (tid < NB) nfs[tid] = nodes[blk * NB + tid];
    __syncthreads();
    if (tid < NB * 10) {                       // 160 threads: 1-hop
        const int i = tid / 10, s = tid - (tid / 10) * 10;
        idx[i][s] = n1[nfs[i] * 10 + s];
    }
    if (tid >= 96) {                           // 160 threads: 2-hop seeds
        const int t = tid - 96;
        const int i = t / 10, s = t - (t / 10) * 10;
        sm_m[i][s] = n2[nfs[i] * 10 + s];
    }
    if (tid < NB) idx[tid][110] = nfs[tid];
    __syncthreads();
    for (int t = tid; t < NB * 100; t += 256) { // 1600 two-hop rows
        const int i = t / 100, rr = t - (t / 100) * 100;
        idx[i][10 + rr] = n1[sm_m[i][rr / 10] * 10 + (rr - (rr / 10) * 10)];
    }
    __syncthreads();

    // ---- phase 2: gather (r13 sequential-chunk loop, all-fp8; self fp32 at END) ----
    {
        const int g = tid >> 4;    // node_local 0..15
        const int l = tid & 15;    // dims l*8 .. l*8+7
        const unsigned char* Tl8 = T8 + l * 8;

        float aA[8] = {0,0,0,0,0,0,0,0};
        float aB[8] = {0,0,0,0,0,0,0,0};

        {   // chunk 0: rows 0..9 -> 1-hop (fp8)
            uint2 v[10];
#pragma unroll
            for (int s = 0; s < 10; ++s)
                v[s] = *(const uint2*)(Tl8 + (size_t)idx[g][s] * FEAT);
#pragma unroll
            for (int s = 0; s < 10; ++s) acc8f8(aA, v[s]);
        }
        // chunks 1..10: rows 10..109 -> 2-hop (fp8)
#pragma unroll
        for (int c = 1; c <= 10; ++c) {
            uint2 v[10];
#pragma unroll
            for (int s = 0; s < 10; ++s)
                v[s] = *(const uint2*)(Tl8 + (size_t)idx[g][c * 10 + s] * FEAT);
#pragma unroll
            for (int s = 0; s < 10; ++s) acc8f8(aB, v[s]);
        }
        *(uint4*)&X[g * 3 + 0][l * 8] = pack8(aA, 0.1f);
        *(uint4*)&X[g * 3 + 1][l * 8] = pack8(aB, 0.01f);

        // self row (fp32, exact) — loaded LAST so its 8 regs don't live across gather
        const float* Fs = featF + (size_t)idx[g][110] * FEAT + l * 8;
        const f32x4 s0 = *(const f32x4*)Fs;
        const f32x4 s1 = *(const f32x4*)(Fs + 4);
        float aS[8] = {s0[0], s0[1], s0[2], s0[3], s1[0], s1[1], s1[2], s1[3]};
        *(uint4*)&X[g * 3 + 2][l * 8] = pack8(aS, 1.0f);
    }
    __syncthreads();

    // ---- phase 3: GEMM M=48 x N=1024 x K=128 + ReLU (r11-verified verbatim) ----
    const int wave = tid >> 6;
    const int lane = tid & 63;
    const int r = lane & 15;   // A row / B col within 16-tile
    const int q = lane >> 4;   // k-slot (8 contiguous K elems)

#pragma unroll
    for (int ch = 0; ch < 4; ++ch) {
        const int yBase = wave * 256 + ch * 64;
        f32x4 acc[3][4];
#pragma unroll
        for (int mt = 0; mt < 3; ++mt)
#pragma unroll
            for (int nj = 0; nj < 4; ++nj) acc[mt][nj] = (f32x4){0.f, 0.f, 0.f, 0.f};

#pragma unroll
        for (int k0 = 0; k0 < 4; ++k0) {
            bf16x8 a[3], b[4];
#pragma unroll
            for (int mt = 0; mt < 3; ++mt)
                a[mt] = *(const bf16x8*)&X[mt * 16 + r][k0 * 32 + q * 8];
#pragma unroll
            for (int nj = 0; nj < 4; ++nj)
                b[nj] = *(const bf16x8*)(Wp + (size_t)(yBase + nj * 16 + r) * FEAT
                                            + q * 8 + k0 * 32);
#pragma unroll
            for (int mt = 0; mt < 3; ++mt)
#pragma unroll
                for (int nj = 0; nj < 4; ++nj)
                    acc[mt][nj] = __builtin_amdgcn_mfma_f32_16x16x32_bf16(
                        a[mt], b[nj], acc[mt][nj], 0, 0, 0);
        }

        // scattered epilogue (r11-verified): C/D row = q*4+i, col = r.
#pragma unroll
        for (int mt = 0; mt < 3; ++mt) {
#pragma unroll
            for (int i = 0; i < 4; ++i) {
                const int xl = mt * 16 + q * 4 + i;   // 0..47
                const int nl = xl / 3;
                const int j  = xl - nl * 3;
                float* orow = out + (size_t)(blk * NB + nl) * 3072 + j * 128;
#pragma unroll
                for (int nj = 0; nj < 4; ++nj) {
                    const int y = yBase + nj * 16 + r;
                    const int c = y >> 7;
                    const int k = y & 127;
                    orow[c * 384 + k] = fmaxf(acc[mt][nj][i], 0.f);
                }
            }
        }
    }
}

extern "C" void kernel_launch(void* const* d_in, const int* in_sizes, int n_in,
                              void* d_out, int out_size, void* d_ws, size_t ws_size,
                              hipStream_t stream) {
    const float* features = (const float*)d_in[0];   // [100000,128] f32
    const float* lw       = (const float*)d_in[1];   // [8,128,128]  f32
    const int*   nodes    = (const int*)d_in[2];     // [1024,8]     i32
    const int*   n1       = (const int*)d_in[3];     // [100000,10]  i32
    const int*   n2       = (const int*)d_in[4];     // [100000,10]  i32
    float*       out      = (float*)d_out;           // [1024,8,8,384] f32

    unsigned short* Wp = (unsigned short*)d_ws;              // 1024*128 bf16 = 256 KB
    unsigned char*  T8 = (unsigned char*)(Wp + (size_t)1024 * FEAT);  // 12.8 MB fp8

    pack_all<<<F8_BLOCKS + 128, 256, 0, stream>>>(features, lw, T8, Wp);
    fused_enc<<<NBLK, 256, 0, stream>>>(T8, features, nodes, n1, n2, Wp, out);
}

// Round 18
// 72.975 us; speedup vs baseline: 1.1193x; 1.0053x over previous
//
#include <hip/hip_runtime.h>

typedef __attribute__((ext_vector_type(8))) short bf16x8;
typedef __attribute__((ext_vector_type(4))) float f32x4;

static constexpr int N_NODES = 8192;   // B*L
static constexpr int FEAT    = 128;
static constexpr int NB      = 16;     // nodes per fused block
static constexpr int NBLK    = N_NODES / NB;   // 512 blocks
static constexpr int XS      = 136;    // LDS X row stride (bf16): 272B, 16B-aligned
static constexpr int F8_BLOCKS = 3125; // 100000*128 fp8 bytes / (256 thr * 16 B)

__device__ __forceinline__ unsigned short f2bf(float f) {
    unsigned u = __builtin_bit_cast(unsigned, f);
    u += 0x7FFFu + ((u >> 16) & 1u);   // round-to-nearest-even
    return (unsigned short)(u >> 16);
}
// f32 -> e4m3fn, RNE, satfinite (r13-verified). af*2^-120 puts the e4m3
// em-field at f32 bits [26:20] (exact incl. subnormals); round at bit 20.
__device__ __forceinline__ unsigned f2fp8(float f) {
    unsigned u = __builtin_bit_cast(unsigned, f);
    unsigned s = (u >> 24) & 0x80u;
    float af = __builtin_bit_cast(float, u & 0x7fffffffu);
    if (!(af < 448.f)) af = 448.f;
    unsigned q = __builtin_bit_cast(unsigned, af * 0x1p-120f);
    unsigned b = (q + 0x7FFFFu + ((q >> 20) & 1u)) >> 20;
    return s | b;
}
// e4m3fn decode+accumulate (r13-verified): byte to top, ashr 4, mask, fma 2^120.
__device__ __forceinline__ void acc8f8(float* a, const uint2 v) {
#pragma unroll
    for (int i = 0; i < 4; ++i) {
        unsigned t = v.x << (24 - 8 * i);
        unsigned w = (unsigned)((int)t >> 4) & 0x87F00000u;
        a[i] = fmaf(__builtin_bit_cast(float, w), 0x1p120f, a[i]);
    }
#pragma unroll
    for (int i = 0; i < 4; ++i) {
        unsigned t = v.y << (24 - 8 * i);
        unsigned w = (unsigned)((int)t >> 4) & 0x87F00000u;
        a[4 + i] = fmaf(__builtin_bit_cast(float, w), 0x1p120f, a[4 + i]);
    }
}
__device__ __forceinline__ uint4 pack8(const float* a, float sc) {
    uint4 o;
    o.x = (unsigned)f2bf(a[0] * sc) | ((unsigned)f2bf(a[1] * sc) << 16);
    o.y = (unsigned)f2bf(a[2] * sc) | ((unsigned)f2bf(a[3] * sc) << 16);
    o.z = (unsigned)f2bf(a[4] * sc) | ((unsigned)f2bf(a[5] * sc) << 16);
    o.w = (unsigned)f2bf(a[6] * sc) | ((unsigned)f2bf(a[7] * sc) << 16);
    return o;
}

// ---------------- Kernel 0: pack features fp32 -> fp8, W fp32 -> bf16 ----------------
__global__ void __launch_bounds__(256) pack_all(
    const float* __restrict__ feat, const float* __restrict__ lw,
    unsigned char* __restrict__ T8, unsigned short* __restrict__ Wp)
{
    const int b = blockIdx.x;
    if (b < F8_BLOCKS) {
        const size_t i = (size_t)b * 256 + threadIdx.x;   // handles 16 floats
        const f32x4* src = (const f32x4*)feat + i * 4;
        uint4 p;
        unsigned* pw = (unsigned*)&p;
#pragma unroll
        for (int h = 0; h < 4; ++h) {
            const f32x4 v = __builtin_nontemporal_load(src + h);
            pw[h] = f2fp8(v[0]) | (f2fp8(v[1]) << 8) | (f2fp8(v[2]) << 16) | (f2fp8(v[3]) << 24);
        }
        ((uint4*)T8)[i] = p;
    } else {
        const int i = (b - F8_BLOCKS) * 256 + threadIdx.x;
        const float4 v = ((const float4*)lw)[i];
        ushort4 o;
        o.x = f2bf(v.x); o.y = f2bf(v.y); o.z = f2bf(v.z); o.w = f2bf(v.w);
        ((ushort4*)Wp)[i] = o;
    }
}

// ---------------- Fused: gather (fp8) -> LDS X -> MFMA GEMM + ReLU ----------------
// No launch_bounds (r16 lesson: forcing 4 blk/CU spilled, +32MB scratch traffic).
// Self fp32 row loaded at tail (r15 lesson: early load -> 132 VGPR -> occ halved).
// Output stores nontemporal (keep fp8 table L2-resident vs 98MB store stream).
__global__ void __launch_bounds__(256) fused_enc(
    const unsigned char*  __restrict__ T8,
    const float* __restrict__ featF,
    const int*   __restrict__ nodes,
    const int*   __restrict__ n1,
    const int*   __restrict__ n2,
    const unsigned short* __restrict__ Wp,
    float* __restrict__ out)
{
    __shared__ int nfs[NB];
    __shared__ int sm_m[NB][10];
    __shared__ int idx[NB][112];              // [0..9]=1hop, [10..109]=2hop, [110]=self
    __shared__ unsigned short X[3 * NB][XS];  // 48 x 136 bf16

    const int blk = blockIdx.x;
    const int tid = threadIdx.x;

    // ---- phase 1: indices (r11-verified) ----
    if (tid < NB) nfs[tid] = nodes[blk * NB + tid];
    __syncthreads();
    if (tid < NB * 10) {                       // 160 threads: 1-hop
        const int i = tid / 10, s = tid - (tid / 10) * 10;
        idx[i][s] = n1[nfs[i] * 10 + s];
    }
    if (tid >= 96) {                           // 160 threads: 2-hop seeds
        const int t = tid - 96;
        const int i = t / 10, s = t - (t / 10) * 10;
        sm_m[i][s] = n2[nfs[i] * 10 + s];
    }
    if (tid < NB) idx[tid][110] = nfs[tid];
    __syncthreads();
    for (int t = tid; t < NB * 100; t += 256) { // 1600 two-hop rows
        const int i = t / 100, rr = t - (t / 100) * 100;
        idx[i][10 + rr] = n1[sm_m[i][rr / 10] * 10 + (rr - (rr / 10) * 10)];
    }
    __syncthreads();

    // ---- phase 2: gather (r13 sequential-chunk loop, all-fp8; self fp32 at END) ----
    {
        const int g = tid >> 4;    // node_local 0..15
        const int l = tid & 15;    // dims l*8 .. l*8+7
        const unsigned char* Tl8 = T8 + l * 8;

        float aA[8] = {0,0,0,0,0,0,0,0};
        float aB[8] = {0,0,0,0,0,0,0,0};

        {   // chunk 0: rows 0..9 -> 1-hop (fp8)
            uint2 v[10];
#pragma unroll
            for (int s = 0; s < 10; ++s)
                v[s] = *(const uint2*)(Tl8 + (size_t)idx[g][s] * FEAT);
#pragma unroll
            for (int s = 0; s < 10; ++s) acc8f8(aA, v[s]);
        }
        // chunks 1..10: rows 10..109 -> 2-hop (fp8)
#pragma unroll
        for (int c = 1; c <= 10; ++c) {
            uint2 v[10];
#pragma unroll
            for (int s = 0; s < 10; ++s)
                v[s] = *(const uint2*)(Tl8 + (size_t)idx[g][c * 10 + s] * FEAT);
#pragma unroll
            for (int s = 0; s < 10; ++s) acc8f8(aB, v[s]);
        }
        *(uint4*)&X[g * 3 + 0][l * 8] = pack8(aA, 0.1f);
        *(uint4*)&X[g * 3 + 1][l * 8] = pack8(aB, 0.01f);

        // self row (fp32, exact) — loaded LAST so its 8 regs don't live across gather
        const float* Fs = featF + (size_t)idx[g][110] * FEAT + l * 8;
        const f32x4 s0 = *(const f32x4*)Fs;
        const f32x4 s1 = *(const f32x4*)(Fs + 4);
        float aS[8] = {s0[0], s0[1], s0[2], s0[3], s1[0], s1[1], s1[2], s1[3]};
        *(uint4*)&X[g * 3 + 2][l * 8] = pack8(aS, 1.0f);
    }
    __syncthreads();

    // ---- phase 3: GEMM M=48 x N=1024 x K=128 + ReLU (r11-verified verbatim) ----
    const int wave = tid >> 6;
    const int lane = tid & 63;
    const int r = lane & 15;   // A row / B col within 16-tile
    const int q = lane >> 4;   // k-slot (8 contiguous K elems)

#pragma unroll
    for (int ch = 0; ch < 4; ++ch) {
        const int yBase = wave * 256 + ch * 64;
        f32x4 acc[3][4];
#pragma unroll
        for (int mt = 0; mt < 3; ++mt)
#pragma unroll
            for (int nj = 0; nj < 4; ++nj) acc[mt][nj] = (f32x4){0.f, 0.f, 0.f, 0.f};

#pragma unroll
        for (int k0 = 0; k0 < 4; ++k0) {
            bf16x8 a[3], b[4];
#pragma unroll
            for (int mt = 0; mt < 3; ++mt)
                a[mt] = *(const bf16x8*)&X[mt * 16 + r][k0 * 32 + q * 8];
#pragma unroll
            for (int nj = 0; nj < 4; ++nj)
                b[nj] = *(const bf16x8*)(Wp + (size_t)(yBase + nj * 16 + r) * FEAT
                                            + q * 8 + k0 * 32);
#pragma unroll
            for (int mt = 0; mt < 3; ++mt)
#pragma unroll
                for (int nj = 0; nj < 4; ++nj)
                    acc[mt][nj] = __builtin_amdgcn_mfma_f32_16x16x32_bf16(
                        a[mt], b[nj], acc[mt][nj], 0, 0, 0);
        }

        // scattered epilogue (r11-verified mapping), nontemporal stores.
#pragma unroll
        for (int mt = 0; mt < 3; ++mt) {
#pragma unroll
            for (int i = 0; i < 4; ++i) {
                const int xl = mt * 16 + q * 4 + i;   // 0..47
                const int nl = xl / 3;
                const int j  = xl - nl * 3;
                float* orow = out + (size_t)(blk * NB + nl) * 3072 + j * 128;
#pragma unroll
                for (int nj = 0; nj < 4; ++nj) {
                    const int y = yBase + nj * 16 + r;
                    const int c = y >> 7;
                    const int k = y & 127;
                    __builtin_nontemporal_store(fmaxf(acc[mt][nj][i], 0.f),
                                                &orow[c * 384 + k]);
                }
            }
        }
    }
}

extern "C" void kernel_launch(void* const* d_in, const int* in_sizes, int n_in,
                              void* d_out, int out_size, void* d_ws, size_t ws_size,
                              hipStream_t stream) {
    const float* features = (const float*)d_in[0];   // [100000,128] f32
    const float* lw       = (const float*)d_in[1];   // [8,128,128]  f32
    const int*   nodes    = (const int*)d_in[2];     // [1024,8]     i32
    const int*   n1       = (const int*)d_in[3];     // [100000,10]  i32
    const int*   n2       = (const int*)d_in[4];     // [100000,10]  i32
    float*       out      = (float*)d_out;           // [1024,8,8,384] f32

    unsigned short* Wp = (unsigned short*)d_ws;              // 1024*128 bf16 = 256 KB
    unsigned char*  T8 = (unsigned char*)(Wp + (size_t)1024 * FEAT);  // 12.8 MB fp8

    pack_all<<<F8_BLOCKS + 128, 256, 0, stream>>>(features, lw, T8, Wp);
    fused_enc<<<NBLK, 256, 0, stream>>>(T8, features, nodes, n1, n2, Wp, out);
}

// Round 19
// 65.879 us; speedup vs baseline: 1.2398x; 1.1077x over previous
//
#include <hip/hip_runtime.h>

typedef __attribute__((ext_vector_type(8))) short bf16x8;
typedef __attribute__((ext_vector_type(4))) float f32x4;

static constexpr int N_NODES = 8192;   // B*L
static constexpr int FEAT    = 128;
static constexpr int NB      = 16;     // nodes per fused block
static constexpr int NBLK    = N_NODES / NB;   // 512 blocks
static constexpr int XS      = 136;    // LDS X row stride (bf16): 272B, 16B-aligned
static constexpr int F8_BLOCKS = 3125; // 100000*128 fp8 bytes / (256 thr * 16 B)

__device__ __forceinline__ unsigned short f2bf(float f) {
    unsigned u = __builtin_bit_cast(unsigned, f);
    u += 0x7FFFu + ((u >> 16) & 1u);   // round-to-nearest-even
    return (unsigned short)(u >> 16);
}
// f32 -> e4m3fn, RNE, satfinite (r13-verified). af*2^-120 puts the e4m3
// em-field at f32 bits [26:20] (exact incl. subnormals); round at bit 20.
__device__ __forceinline__ unsigned f2fp8(float f) {
    unsigned u = __builtin_bit_cast(unsigned, f);
    unsigned s = (u >> 24) & 0x80u;
    float af = __builtin_bit_cast(float, u & 0x7fffffffu);
    if (!(af < 448.f)) af = 448.f;
    unsigned q = __builtin_bit_cast(unsigned, af * 0x1p-120f);
    unsigned b = (q + 0x7FFFFu + ((q >> 20) & 1u)) >> 20;
    return s | b;
}
// e4m3fn decode+accumulate (r13-verified): byte to top, ashr 4, mask, fma 2^120.
__device__ __forceinline__ void acc8f8(float* a, const uint2 v) {
#pragma unroll
    for (int i = 0; i < 4; ++i) {
        unsigned t = v.x << (24 - 8 * i);
        unsigned w = (unsigned)((int)t >> 4) & 0x87F00000u;
        a[i] = fmaf(__builtin_bit_cast(float, w), 0x1p120f, a[i]);
    }
#pragma unroll
    for (int i = 0; i < 4; ++i) {
        unsigned t = v.y << (24 - 8 * i);
        unsigned w = (unsigned)((int)t >> 4) & 0x87F00000u;
        a[4 + i] = fmaf(__builtin_bit_cast(float, w), 0x1p120f, a[4 + i]);
    }
}
__device__ __forceinline__ uint4 pack8(const float* a, float sc) {
    uint4 o;
    o.x = (unsigned)f2bf(a[0] * sc) | ((unsigned)f2bf(a[1] * sc) << 16);
    o.y = (unsigned)f2bf(a[2] * sc) | ((unsigned)f2bf(a[3] * sc) << 16);
    o.z = (unsigned)f2bf(a[4] * sc) | ((unsigned)f2bf(a[5] * sc) << 16);
    o.w = (unsigned)f2bf(a[6] * sc) | ((unsigned)f2bf(a[7] * sc) << 16);
    return o;
}

// ---------------- Kernel 0: pack features fp32 -> fp8, W fp32 -> bf16 ----------------
__global__ void __launch_bounds__(256) pack_all(
    const float* __restrict__ feat, const float* __restrict__ lw,
    unsigned char* __restrict__ T8, unsigned short* __restrict__ Wp)
{
    const int b = blockIdx.x;
    if (b < F8_BLOCKS) {
        const size_t i = (size_t)b * 256 + threadIdx.x;   // handles 16 floats
        const f32x4* src = (const f32x4*)feat + i * 4;
        uint4 p;
        unsigned* pw = (unsigned*)&p;
#pragma unroll
        for (int h = 0; h < 4; ++h) {
            const f32x4 v = __builtin_nontemporal_load(src + h);
            pw[h] = f2fp8(v[0]) | (f2fp8(v[1]) << 8) | (f2fp8(v[2]) << 16) | (f2fp8(v[3]) << 24);
        }
        ((uint4*)T8)[i] = p;
    } else {
        const int i = (b - F8_BLOCKS) * 256 + threadIdx.x;
        const float4 v = ((const float4*)lw)[i];
        ushort4 o;
        o.x = f2bf(v.x); o.y = f2bf(v.y); o.z = f2bf(v.z); o.w = f2bf(v.w);
        ((ushort4*)Wp)[i] = o;
    }
}

// ---------------- Fused: gather (fp8) -> LDS X -> MFMA GEMM + ReLU ----------------
// No launch_bounds (r16: forcing 4 blk/CU spilled). Self fp32 at tail (r15: early
// load -> 132 VGPR -> occ halved). PLAIN output stores (r18: scattered nt-stores
// caused +25% partial-line write amplification, 98->123 MB).
__global__ void __launch_bounds__(256) fused_enc(
    const unsigned char*  __restrict__ T8,
    const float* __restrict__ featF,
    const int*   __restrict__ nodes,
    const int*   __restrict__ n1,
    const int*   __restrict__ n2,
    const unsigned short* __restrict__ Wp,
    float* __restrict__ out)
{
    __shared__ int nfs[NB];
    __shared__ int sm_m[NB][10];
    __shared__ int idx[NB][112];              // [0..9]=1hop, [10..109]=2hop, [110]=self
    __shared__ unsigned short X[3 * NB][XS];  // 48 x 136 bf16

    const int blk = blockIdx.x;
    const int tid = threadIdx.x;

    // ---- phase 1: indices (r11-verified) ----
    if (tid < NB) nfs[tid] = nodes[blk * NB + tid];
    __syncthreads();
    if (tid < NB * 10) {                       // 160 threads: 1-hop
        const int i = tid / 10, s = tid - (tid / 10) * 10;
        idx[i][s] = n1[nfs[i] * 10 + s];
    }
    if (tid >= 96) {                           // 160 threads: 2-hop seeds
        const int t = tid - 96;
        const int i = t / 10, s = t - (t / 10) * 10;
        sm_m[i][s] = n2[nfs[i] * 10 + s];
    }
    if (tid < NB) idx[tid][110] = nfs[tid];
    __syncthreads();
    for (int t = tid; t < NB * 100; t += 256) { // 1600 two-hop rows
        const int i = t / 100, rr = t - (t / 100) * 100;
        idx[i][10 + rr] = n1[sm_m[i][rr / 10] * 10 + (rr - (rr / 10) * 10)];
    }
    __syncthreads();

    // ---- phase 2: gather (r13 sequential-chunk loop, all-fp8; self fp32 at END) ----
    {
        const int g = tid >> 4;    // node_local 0..15
        const int l = tid & 15;    // dims l*8 .. l*8+7
        const unsigned char* Tl8 = T8 + l * 8;

        float aA[8] = {0,0,0,0,0,0,0,0};
        float aB[8] = {0,0,0,0,0,0,0,0};

        {   // chunk 0: rows 0..9 -> 1-hop (fp8)
            uint2 v[10];
#pragma unroll
            for (int s = 0; s < 10; ++s)
                v[s] = *(const uint2*)(Tl8 + (size_t)idx[g][s] * FEAT);
#pragma unroll
            for (int s = 0; s < 10; ++s) acc8f8(aA, v[s]);
        }
        // chunks 1..10: rows 10..109 -> 2-hop (fp8)
#pragma unroll
        for (int c = 1; c <= 10; ++c) {
            uint2 v[10];
#pragma unroll
            for (int s = 0; s < 10; ++s)
                v[s] = *(const uint2*)(Tl8 + (size_t)idx[g][c * 10 + s] * FEAT);
#pragma unroll
            for (int s = 0; s < 10; ++s) acc8f8(aB, v[s]);
        }
        *(uint4*)&X[g * 3 + 0][l * 8] = pack8(aA, 0.1f);
        *(uint4*)&X[g * 3 + 1][l * 8] = pack8(aB, 0.01f);

        // self row (fp32, exact) — loaded LAST so its 8 regs don't live across gather
        const float* Fs = featF + (size_t)idx[g][110] * FEAT + l * 8;
        const f32x4 s0 = *(const f32x4*)Fs;
        const f32x4 s1 = *(const f32x4*)(Fs + 4);
        float aS[8] = {s0[0], s0[1], s0[2], s0[3], s1[0], s1[1], s1[2], s1[3]};
        *(uint4*)&X[g * 3 + 2][l * 8] = pack8(aS, 1.0f);
    }
    __syncthreads();

    // ---- phase 3: GEMM M=48 x N=1024 x K=128 + ReLU (r11-verified verbatim) ----
    const int wave = tid >> 6;
    const int lane = tid & 63;
    const int r = lane & 15;   // A row / B col within 16-tile
    const int q = lane >> 4;   // k-slot (8 contiguous K elems)

#pragma unroll
    for (int ch = 0; ch < 4; ++ch) {
        const int yBase = wave * 256 + ch * 64;
        f32x4 acc[3][4];
#pragma unroll
        for (int mt = 0; mt < 3; ++mt)
#pragma unroll
            for (int nj = 0; nj < 4; ++nj) acc[mt][nj] = (f32x4){0.f, 0.f, 0.f, 0.f};

#pragma unroll
        for (int k0 = 0; k0 < 4; ++k0) {
            bf16x8 a[3], b[4];
#pragma unroll
            for (int mt = 0; mt < 3; ++mt)
                a[mt] = *(const bf16x8*)&X[mt * 16 + r][k0 * 32 + q * 8];
#pragma unroll
            for (int nj = 0; nj < 4; ++nj)
                b[nj] = *(const bf16x8*)(Wp + (size_t)(yBase + nj * 16 + r) * FEAT
                                            + q * 8 + k0 * 32);
#pragma unroll
            for (int mt = 0; mt < 3; ++mt)
#pragma unroll
                for (int nj = 0; nj < 4; ++nj)
                    acc[mt][nj] = __builtin_amdgcn_mfma_f32_16x16x32_bf16(
                        a[mt], b[nj], acc[mt][nj], 0, 0, 0);
        }

        // scattered epilogue (r11-verified), PLAIN stores.
#pragma unroll
        for (int mt = 0; mt < 3; ++mt) {
#pragma unroll
            for (int i = 0; i < 4; ++i) {
                const int xl = mt * 16 + q * 4 + i;   // 0..47
                const int nl = xl / 3;
                const int j  = xl - nl * 3;
                float* orow = out + (size_t)(blk * NB + nl) * 3072 + j * 128;
#pragma unroll
                for (int nj = 0; nj < 4; ++nj) {
                    const int y = yBase + nj * 16 + r;
                    const int c = y >> 7;
                    const int k = y & 127;
                    orow[c * 384 + k] = fmaxf(acc[mt][nj][i], 0.f);
                }
            }
        }
    }
}

extern "C" void kernel_launch(void* const* d_in, const int* in_sizes, int n_in,
                              void* d_out, int out_size, void* d_ws, size_t ws_size,
                              hipStream_t stream) {
    const float* features = (const float*)d_in[0];   // [100000,128] f32
    const float* lw       = (const float*)d_in[1];   // [8,128,128]  f32
    const int*   nodes    = (const int*)d_in[2];     // [1024,8]     i32
    const int*   n1       = (const int*)d_in[3];     // [100000,10]  i32
    const int*   n2       = (const int*)d_in[4];     // [100000,10]  i32
    float*       out      = (float*)d_out;           // [1024,8,8,384] f32

    unsigned short* Wp = (unsigned short*)d_ws;              // 1024*128 bf16 = 256 KB
    unsigned char*  T8 = (unsigned char*)(Wp + (size_t)1024 * FEAT);  // 12.8 MB fp8

    pack_all<<<F8_BLOCKS + 128, 256, 0, stream>>>(features, lw, T8, Wp);
    fused_enc<<<NBLK, 256, 0, stream>>>(T8, features, nodes, n1, n2, Wp, out);
}